// Round 1
// baseline (88.820 us; speedup 1.0000x reference)
//
#include <hip/hip_runtime.h>
#include <stdint.h>

#define NB   8
#define INC  64
#define INN  20000
#define OUTC 64
#define OUTN 8000
#define MAXD 32
#define NG   16   // groups of 4 input channels

// ---------- helpers ----------
__device__ __forceinline__ uint32_t pack_bf16_2(float a, float b) {
    uint32_t ua = __float_as_uint(a);
    uint32_t ub = __float_as_uint(b);
    uint32_t ra = (ua + 0x7FFFu + ((ua >> 16) & 1u)) >> 16;   // RTNE
    uint32_t rb = (ub + 0x7FFFu + ((ub >> 16) & 1u)) >> 16;
    return (ra & 0xFFFFu) | (rb << 16);
}

// ---------- kernel 0: transpose A, per-o scale, W^T ----------
__global__ void prep_kernel(const int* __restrict__ A, const float* __restrict__ mask,
                            const float* __restrict__ ct_v, const float* __restrict__ ct_g,
                            int* __restrict__ A_T, float2* __restrict__ scale2,
                            float* __restrict__ W_T) {
    if (blockIdx.x == 64) {
        int k = threadIdx.x;
        if (k < OUTC) {
            float s = 0.f;
            for (int c = 0; c < INC; ++c) { float v = ct_v[k * INC + c]; s += v * v; }
            float inv = ct_g[k] / sqrtf(s);
            for (int c = 0; c < INC; ++c) W_T[c * OUTC + k] = ct_v[k * INC + c] * inv;
        }
        return;
    }
    int o = blockIdx.x * 128 + threadIdx.x;
    if (o >= OUTN) return;
    const int4* arow = (const int4*)(A + (size_t)o * MAXD);
#pragma unroll
    for (int q = 0; q < 8; ++q) {
        int4 v = arow[q];
        A_T[(q * 4 + 0) * OUTN + o] = v.x;
        A_T[(q * 4 + 1) * OUTN + o] = v.y;
        A_T[(q * 4 + 2) * OUTN + o] = v.z;
        A_T[(q * 4 + 3) * OUTN + o] = v.w;
    }
    float invdeg = mask[(size_t)o * MAXD];          // mask[o][0] = 1/deg (deg>=8)
    float deg    = rintf(1.0f / invdeg);
    scale2[o] = make_float2(invdeg, 32.0f - deg);
}

// ---------- kernel 1: xw = x*weight, packed 4 channels of bf16 ----------
__global__ __launch_bounds__(256)
void xw_kernel(const float* __restrict__ x, const float* __restrict__ w,
               uint2* __restrict__ xwi) {
    int t    = threadIdx.x;
    int tile = blockIdx.x;          // 0..19
    int g    = blockIdx.y;          // 0..15
    int b    = blockIdx.z;          // 0..7
    int i0   = tile * 1024 + t * 4;
    if (i0 >= INN) return;
    float4 p[4];
#pragma unroll
    for (int cl = 0; cl < 4; ++cl) {
        int c = g * 4 + cl;
        float4 xv = *(const float4*)(x + ((size_t)(b * INC + c)) * INN + i0);
        float4 wv = *(const float4*)(w + (size_t)c * INN + i0);
        p[cl] = make_float4(xv.x * wv.x, xv.y * wv.y, xv.z * wv.z, xv.w * wv.w);
    }
    // per-i word pair: low word = (c0,c1), high word = (c2,c3)
    uint4 o01, o23;
    o01.x = pack_bf16_2(p[0].x, p[1].x);  o01.y = pack_bf16_2(p[2].x, p[3].x);
    o01.z = pack_bf16_2(p[0].y, p[1].y);  o01.w = pack_bf16_2(p[2].y, p[3].y);
    o23.x = pack_bf16_2(p[0].z, p[1].z);  o23.y = pack_bf16_2(p[2].z, p[3].z);
    o23.z = pack_bf16_2(p[0].w, p[1].w);  o23.w = pack_bf16_2(p[2].w, p[3].w);
    uint2* dst = xwi + ((size_t)(b * NG + g)) * INN + i0;
    ((uint4*)dst)[0] = o01;
    ((uint4*)dst)[1] = o23;
}

// ---------- kernel 2: gather-pool from LDS (4 channels per ds_read_b64) ----------
__global__ __launch_bounds__(512, 1)
void gather_kernel(const uint2* __restrict__ xwi, const int* __restrict__ A_T,
                   const float2* __restrict__ scale2, float* __restrict__ pooled) {
    __shared__ __align__(16) uint2 smem[INN];   // 160,000 B (<= 160 KiB on gfx950)
    int h = blockIdx.x;          // 0..1  (o-range half)
    int g = blockIdx.y;          // 0..15
    int b = blockIdx.z;          // 0..7

    const uint4* src = (const uint4*)(xwi + ((size_t)(b * NG + g)) * INN);
    uint4* sm4 = (uint4*)smem;
    for (int i = threadIdx.x; i < INN / 2; i += 512) sm4[i] = src[i];
    __syncthreads();

    uint2 z0 = smem[0];
    float z00 = __uint_as_float(z0.x << 16);
    float z01 = __uint_as_float(z0.x & 0xFFFF0000u);
    float z02 = __uint_as_float(z0.y << 16);
    float z03 = __uint_as_float(z0.y & 0xFFFF0000u);

    int obase = h * (OUTN / 2);
    int oend  = obase + (OUTN / 2);
    for (int o = obase + threadIdx.x; o < oend; o += 512) {
        float a0 = 0.f, a1 = 0.f, a2 = 0.f, a3 = 0.f;
#pragma unroll
        for (int d = 0; d < MAXD; ++d) {
            int idx = A_T[d * OUTN + o];
            uint2 v = smem[idx];
            a0 += __uint_as_float(v.x << 16);
            a1 += __uint_as_float(v.x & 0xFFFF0000u);
            a2 += __uint_as_float(v.y << 16);
            a3 += __uint_as_float(v.y & 0xFFFF0000u);
        }
        float2 sc = scale2[o];   // {1/deg, 32-deg}
        a0 = (a0 - sc.y * z00) * sc.x;
        a1 = (a1 - sc.y * z01) * sc.x;
        a2 = (a2 - sc.y * z02) * sc.x;
        a3 = (a3 - sc.y * z03) * sc.x;
        int c0 = g * 4;
        pooled[((size_t)(b * OUTC + c0 + 0)) * OUTN + o] = a0;
        pooled[((size_t)(b * OUTC + c0 + 1)) * OUTN + o] = a1;
        pooled[((size_t)(b * OUTC + c0 + 2)) * OUTN + o] = a2;
        pooled[((size_t)(b * OUTC + c0 + 3)) * OUTN + o] = a3;
    }
}

// ---------- kernel 3: y = W @ pooled + bias (in place over d_out) ----------
__global__ __launch_bounds__(256)
void out_kernel(float* io, const float* __restrict__ W_T,
                const float* __restrict__ bias) {
    __shared__ __align__(16) float sp[INC][128];
    __shared__ __align__(16) float sw[INC][OUTC];
    int obase = blockIdx.x * 128;
    int b     = blockIdx.y;

    const float* pb = io + (size_t)b * INC * OUTN;
    for (int idx = threadIdx.x; idx < INC * 32; idx += 256) {   // 2048 float4
        int c  = idx >> 5;
        int q  = idx & 31;
        int o4 = obase + q * 4;
        float4 v = (o4 < OUTN) ? *(const float4*)(pb + (size_t)c * OUTN + o4)
                               : make_float4(0.f, 0.f, 0.f, 0.f);
        *(float4*)(&sp[c][q * 4]) = v;
    }
    for (int idx = threadIdx.x; idx < (INC * OUTC) / 4; idx += 256) { // 1024 float4
        ((float4*)sw)[idx] = ((const float4*)W_T)[idx];
    }
    __syncthreads();

    int t   = threadIdx.x;
    int kt  = t >> 4;            // 0..15
    int ot0 = (t & 15) * 8;      // 0..120
    int k0  = kt * 4;

    float acc[4][8];
#pragma unroll
    for (int kk = 0; kk < 4; ++kk) {
#pragma unroll
        for (int jh = 0; jh < 2; ++jh) {
            int o4 = obase + ot0 + jh * 4;
            float4 bv = (o4 < OUTN)
                ? *(const float4*)(bias + (size_t)(k0 + kk) * OUTN + o4)
                : make_float4(0.f, 0.f, 0.f, 0.f);
            acc[kk][jh * 4 + 0] = bv.x;
            acc[kk][jh * 4 + 1] = bv.y;
            acc[kk][jh * 4 + 2] = bv.z;
            acc[kk][jh * 4 + 3] = bv.w;
        }
    }

#pragma unroll 4
    for (int c = 0; c < INC; ++c) {
        float4 w4  = *(const float4*)(&sw[c][k0]);
        float4 pa  = *(const float4*)(&sp[c][ot0]);
        float4 pb4 = *(const float4*)(&sp[c][ot0 + 4]);
        float p[8] = {pa.x, pa.y, pa.z, pa.w, pb4.x, pb4.y, pb4.z, pb4.w};
        float wv[4] = {w4.x, w4.y, w4.z, w4.w};
#pragma unroll
        for (int kk = 0; kk < 4; ++kk)
#pragma unroll
            for (int j = 0; j < 8; ++j)
                acc[kk][j] += wv[kk] * p[j];
    }

    int o0 = obase + ot0;
    if (o0 < OUTN) {    // OUTN % 8 == 0 -> whole 8 valid
#pragma unroll
        for (int kk = 0; kk < 4; ++kk) {
            float4 s0 = make_float4(acc[kk][0], acc[kk][1], acc[kk][2], acc[kk][3]);
            float4 s1 = make_float4(acc[kk][4], acc[kk][5], acc[kk][6], acc[kk][7]);
            float* dst = io + ((size_t)(b * OUTC + k0 + kk)) * OUTN + o0;
            *(float4*)(dst)     = s0;
            *(float4*)(dst + 4) = s1;
        }
    }
}

// ---------- launch ----------
extern "C" void kernel_launch(void* const* d_in, const int* in_sizes, int n_in,
                              void* d_out, int out_size, void* d_ws, size_t ws_size,
                              hipStream_t stream) {
    const float* x    = (const float*)d_in[0];
    const float* w    = (const float*)d_in[1];
    const float* ct_v = (const float*)d_in[2];
    const float* ct_g = (const float*)d_in[3];
    const float* bias = (const float*)d_in[4];
    const float* mask = (const float*)d_in[5];
    const int*   A    = (const int*)d_in[6];
    float* y = (float*)d_out;

    char* ws = (char*)d_ws;
    uint2*  xwi    = (uint2*)(ws);                    // 8*16*20000*8  = 20,480,000 B
    int*    A_T    = (int*)(ws + 20480000);           // 32*8000*4    =  1,024,000 B
    float2* scale2 = (float2*)(ws + 21504000);        // 8000*8       =     64,000 B
    float*  W_T    = (float*)(ws + 21568000);         // 64*64*4      =     16,384 B

    prep_kernel<<<65, 128, 0, stream>>>(A, mask, ct_v, ct_g, A_T, scale2, W_T);
    xw_kernel<<<dim3(20, NG, NB), 256, 0, stream>>>(x, w, xwi);
    gather_kernel<<<dim3(2, NG, NB), 512, 0, stream>>>(xwi, A_T, scale2, y);
    out_kernel<<<dim3(63, NB), 256, 0, stream>>>(y, W_T, bias);
}

// Round 2
// 47.743 us; speedup vs baseline: 1.8604x; 1.8604x over previous
//
#include <hip/hip_runtime.h>
#include <stdint.h>

#define NB   8
#define INC  64
#define INN  20000
#define OUTC 64
#define OUTN 8000
#define MAXD 32
#define NG   16   // groups of 4 input channels

// ---------- helpers ----------
__device__ __forceinline__ uint32_t pack_bf16_2(float a, float b) {
    uint32_t ua = __float_as_uint(a);
    uint32_t ub = __float_as_uint(b);
    uint32_t ra = (ua + 0x7FFFu + ((ua >> 16) & 1u)) >> 16;   // RTNE
    uint32_t rb = (ub + 0x7FFFu + ((ub >> 16) & 1u)) >> 16;
    return (ra & 0xFFFFu) | (rb << 16);
}

// ---------- kernel 0: repack A (byte-offset int4 planes), per-o scale, W^T ----------
__global__ void prep_kernel(const int* __restrict__ A, const float* __restrict__ mask,
                            const float* __restrict__ ct_v, const float* __restrict__ ct_g,
                            int4* __restrict__ A4, float2* __restrict__ scale2,
                            float* __restrict__ W_T) {
    if (blockIdx.x == 64) {
        int k = threadIdx.x;
        if (k < OUTC) {
            float s = 0.f;
            for (int c = 0; c < INC; ++c) { float v = ct_v[k * INC + c]; s += v * v; }
            float inv = ct_g[k] / sqrtf(s);
            for (int c = 0; c < INC; ++c) W_T[c * OUTC + k] = ct_v[k * INC + c] * inv;
        }
        return;
    }
    int o = blockIdx.x * 128 + threadIdx.x;
    if (o >= OUTN) return;
    const int4* arow = (const int4*)(A + (size_t)o * MAXD);
#pragma unroll
    for (int q = 0; q < 8; ++q) {
        int4 v = arow[q];
        // pre-scale to byte offsets into uint2-LDS (idx*8)
        v.x <<= 3; v.y <<= 3; v.z <<= 3; v.w <<= 3;
        A4[(size_t)q * OUTN + o] = v;
    }
    float invdeg = mask[(size_t)o * MAXD];          // mask[o][0] = 1/deg (deg>=8)
    float deg    = rintf(1.0f / invdeg);
    scale2[o] = make_float2(invdeg, 32.0f - deg);
}

// ---------- kernel 1: fused xw-staging + gather-pool from LDS ----------
__global__ __launch_bounds__(1024, 1)
void gather_kernel(const float* __restrict__ x, const float* __restrict__ w,
                   const int4* __restrict__ A4, const float2* __restrict__ scale2,
                   float* __restrict__ pooled) {
    __shared__ __align__(16) uint2 smem[INN];   // 160,000 B
    int h = blockIdx.x;          // 0..1  (o-range half)
    int g = blockIdx.y;          // 0..15
    int b = blockIdx.z;          // 0..7
    int tid = threadIdx.x;
    int c0 = g * 4;

    // ---- stage: compute xw = x*w for channels c0..c0+3, pack 4xbf16 per inn-elem ----
    const float* xb = x + ((size_t)b * INC + c0) * INN;
    const float* wb = w + (size_t)c0 * INN;
    for (int p = tid; p < INN / 4; p += 1024) {      // 5000 float4 positions
        int i = p * 4;
        float4 xc[4], wc[4];
#pragma unroll
        for (int cl = 0; cl < 4; ++cl) {
            xc[cl] = *(const float4*)(xb + (size_t)cl * INN + i);
            wc[cl] = *(const float4*)(wb + (size_t)cl * INN + i);
        }
        float p0[4] = {xc[0].x * wc[0].x, xc[0].y * wc[0].y, xc[0].z * wc[0].z, xc[0].w * wc[0].w};
        float p1[4] = {xc[1].x * wc[1].x, xc[1].y * wc[1].y, xc[1].z * wc[1].z, xc[1].w * wc[1].w};
        float p2[4] = {xc[2].x * wc[2].x, xc[2].y * wc[2].y, xc[2].z * wc[2].z, xc[2].w * wc[2].w};
        float p3[4] = {xc[3].x * wc[3].x, xc[3].y * wc[3].y, xc[3].z * wc[3].z, xc[3].w * wc[3].w};
        uint4 lo, hi;
        lo.x = pack_bf16_2(p0[0], p1[0]);  lo.y = pack_bf16_2(p2[0], p3[0]);
        lo.z = pack_bf16_2(p0[1], p1[1]);  lo.w = pack_bf16_2(p2[1], p3[1]);
        hi.x = pack_bf16_2(p0[2], p1[2]);  hi.y = pack_bf16_2(p2[2], p3[2]);
        hi.z = pack_bf16_2(p0[3], p1[3]);  hi.w = pack_bf16_2(p2[3], p3[3]);
        uint4* dst = (uint4*)&smem[i];
        dst[0] = lo;
        dst[1] = hi;
    }
    __syncthreads();

    // correction values (xw[c][0]) — broadcast read
    uint2 z0 = smem[0];
    float z00 = __uint_as_float(z0.x << 16);
    float z01 = __uint_as_float(z0.x & 0xFFFF0000u);
    float z02 = __uint_as_float(z0.y << 16);
    float z03 = __uint_as_float(z0.y & 0xFFFF0000u);

    const char* sbase = (const char*)smem;
    int obase = h * (OUTN / 2);
    int oend  = obase + (OUTN / 2);
#pragma unroll
    for (int it = 0; it < 4; ++it) {
        int o = obase + tid + it * 1024;
        if (o < oend) {
            // 8 coalesced int4 index loads (byte offsets)
            int4 q[8];
#pragma unroll
            for (int dg = 0; dg < 8; ++dg) q[dg] = A4[(size_t)dg * OUTN + o];

            float a0 = 0.f, a1 = 0.f, a2 = 0.f, a3 = 0.f;
#pragma unroll
            for (int dg = 0; dg < 8; ++dg) {
                uint2 v0 = *(const uint2*)(sbase + q[dg].x);
                uint2 v1 = *(const uint2*)(sbase + q[dg].y);
                uint2 v2 = *(const uint2*)(sbase + q[dg].z);
                uint2 v3 = *(const uint2*)(sbase + q[dg].w);
                a0 += __uint_as_float(v0.x << 16);
                a1 += __uint_as_float(v0.x & 0xFFFF0000u);
                a2 += __uint_as_float(v0.y << 16);
                a3 += __uint_as_float(v0.y & 0xFFFF0000u);
                a0 += __uint_as_float(v1.x << 16);
                a1 += __uint_as_float(v1.x & 0xFFFF0000u);
                a2 += __uint_as_float(v1.y << 16);
                a3 += __uint_as_float(v1.y & 0xFFFF0000u);
                a0 += __uint_as_float(v2.x << 16);
                a1 += __uint_as_float(v2.x & 0xFFFF0000u);
                a2 += __uint_as_float(v2.y << 16);
                a3 += __uint_as_float(v2.y & 0xFFFF0000u);
                a0 += __uint_as_float(v3.x << 16);
                a1 += __uint_as_float(v3.x & 0xFFFF0000u);
                a2 += __uint_as_float(v3.y << 16);
                a3 += __uint_as_float(v3.y & 0xFFFF0000u);
            }
            float2 sc = scale2[o];   // {1/deg, 32-deg}
            a0 = (a0 - sc.y * z00) * sc.x;
            a1 = (a1 - sc.y * z01) * sc.x;
            a2 = (a2 - sc.y * z02) * sc.x;
            a3 = (a3 - sc.y * z03) * sc.x;
            pooled[((size_t)(b * OUTC + c0 + 0)) * OUTN + o] = a0;
            pooled[((size_t)(b * OUTC + c0 + 1)) * OUTN + o] = a1;
            pooled[((size_t)(b * OUTC + c0 + 2)) * OUTN + o] = a2;
            pooled[((size_t)(b * OUTC + c0 + 3)) * OUTN + o] = a3;
        }
    }
}

// ---------- kernel 2: y = W @ pooled + bias (in place over d_out) ----------
__global__ __launch_bounds__(256)
void out_kernel(float* io, const float* __restrict__ W_T,
                const float* __restrict__ bias) {
    __shared__ __align__(16) float sp[INC][128];
    __shared__ __align__(16) float sw[INC][OUTC];
    int obase = blockIdx.x * 128;
    int b     = blockIdx.y;

    const float* pb = io + (size_t)b * INC * OUTN;
    for (int idx = threadIdx.x; idx < INC * 32; idx += 256) {   // 2048 float4
        int c  = idx >> 5;
        int q  = idx & 31;
        int o4 = obase + q * 4;
        float4 v = (o4 < OUTN) ? *(const float4*)(pb + (size_t)c * OUTN + o4)
                               : make_float4(0.f, 0.f, 0.f, 0.f);
        *(float4*)(&sp[c][q * 4]) = v;
    }
    for (int idx = threadIdx.x; idx < (INC * OUTC) / 4; idx += 256) { // 1024 float4
        ((float4*)sw)[idx] = ((const float4*)W_T)[idx];
    }
    __syncthreads();

    int t   = threadIdx.x;
    int kt  = t >> 4;            // 0..15
    int ot0 = (t & 15) * 8;      // 0..120
    int k0  = kt * 4;

    float acc[4][8];
#pragma unroll
    for (int kk = 0; kk < 4; ++kk) {
#pragma unroll
        for (int jh = 0; jh < 2; ++jh) {
            int o4 = obase + ot0 + jh * 4;
            float4 bv = (o4 < OUTN)
                ? *(const float4*)(bias + (size_t)(k0 + kk) * OUTN + o4)
                : make_float4(0.f, 0.f, 0.f, 0.f);
            acc[kk][jh * 4 + 0] = bv.x;
            acc[kk][jh * 4 + 1] = bv.y;
            acc[kk][jh * 4 + 2] = bv.z;
            acc[kk][jh * 4 + 3] = bv.w;
        }
    }

#pragma unroll 4
    for (int c = 0; c < INC; ++c) {
        float4 w4  = *(const float4*)(&sw[c][k0]);
        float4 pa  = *(const float4*)(&sp[c][ot0]);
        float4 pb4 = *(const float4*)(&sp[c][ot0 + 4]);
        float p[8] = {pa.x, pa.y, pa.z, pa.w, pb4.x, pb4.y, pb4.z, pb4.w};
        float wv[4] = {w4.x, w4.y, w4.z, w4.w};
#pragma unroll
        for (int kk = 0; kk < 4; ++kk)
#pragma unroll
            for (int j = 0; j < 8; ++j)
                acc[kk][j] += wv[kk] * p[j];
    }

    int o0 = obase + ot0;
    if (o0 < OUTN) {    // OUTN % 8 == 0 -> whole 8 valid
#pragma unroll
        for (int kk = 0; kk < 4; ++kk) {
            float4 s0 = make_float4(acc[kk][0], acc[kk][1], acc[kk][2], acc[kk][3]);
            float4 s1 = make_float4(acc[kk][4], acc[kk][5], acc[kk][6], acc[kk][7]);
            float* dst = io + ((size_t)(b * OUTC + k0 + kk)) * OUTN + o0;
            *(float4*)(dst)     = s0;
            *(float4*)(dst + 4) = s1;
        }
    }
}

// ---------- launch ----------
extern "C" void kernel_launch(void* const* d_in, const int* in_sizes, int n_in,
                              void* d_out, int out_size, void* d_ws, size_t ws_size,
                              hipStream_t stream) {
    const float* x    = (const float*)d_in[0];
    const float* w    = (const float*)d_in[1];
    const float* ct_v = (const float*)d_in[2];
    const float* ct_g = (const float*)d_in[3];
    const float* bias = (const float*)d_in[4];
    const float* mask = (const float*)d_in[5];
    const int*   A    = (const int*)d_in[6];
    float* y = (float*)d_out;

    char* ws = (char*)d_ws;
    int4*   A4     = (int4*)(ws);                     // 8*8000*16 = 1,024,000 B
    float2* scale2 = (float2*)(ws + 1024000);         // 8000*8    =     64,000 B
    float*  W_T    = (float*)(ws + 1088000);          // 64*64*4   =     16,384 B

    prep_kernel<<<65, 128, 0, stream>>>(A, mask, ct_v, ct_g, A4, scale2, W_T);
    gather_kernel<<<dim3(2, NG, NB), 1024, 0, stream>>>(x, w, A4, scale2, y);
    out_kernel<<<dim3(63, NB), 256, 0, stream>>>(y, W_T, bias);
}